// Round 1
// 979.966 us; speedup vs baseline: 1.0586x; 1.0586x over previous
//
#include <hip/hip_runtime.h>
#include <stdint.h>

// Problem constants
#define BB   4
#define NN   16384
#define HH   8
#define DD   512
#define HIDN 2048
#define ROWST (BB * NN)   // 65536 token rows

using short8 = __attribute__((ext_vector_type(8))) short;   // 8 bf16 (4 VGPRs)
using f32x4  = __attribute__((ext_vector_type(4))) float;   // MFMA acc

__device__ __forceinline__ float bf2f(uint16_t h) {
  union { uint32_t u; float f; } v; v.u = ((uint32_t)h) << 16; return v.f;
}
__device__ __forceinline__ uint16_t f2bf(float f) {
  union { float f; uint32_t u; } v; v.f = f;
  return (uint16_t)((v.u + 0x7FFFu + ((v.u >> 16) & 1u)) >> 16);  // RNE
}
// gelu tanh-approx via sigmoid identity
__device__ __forceinline__ float gelu_f(float x) {
  const float t1 = x * x;
  const float inner = __builtin_fmaf(0.044715f * t1, x, x);  // x + 0.044715x^3
  const float e = __expf(-1.5957691216f * inner);            // exp(-2u)
  return x * __builtin_amdgcn_rcpf(1.f + e);
}
// async global->LDS, 16B/lane; LDS dest = wave-uniform base + lane*16
__device__ __forceinline__ void cp16(const uint16_t* g, uint16_t* l) {
  __builtin_amdgcn_global_load_lds((const __attribute__((address_space(1))) void*)g,
                                   (__attribute__((address_space(3))) void*)l, 16, 0, 0);
}
// XOR-swizzled LDS index for transposed [row][64] bf16 tiles (kv/attn kernels).
__device__ __forceinline__ int swz(int row, int col) {
  return row * 64 + (col ^ (row & 56));
}

// ---------------- GEMM 256x128 tile, BK=64, triple-buffered counted-vmcnt pipeline ----
// C[M,N] = A[M,K](bf16) * B^T[N,K](bf16) + epilogue.
// 512 threads = 8 waves as 4(m) x 2(n); per-wave 64x64 output (4x4 16x16 frags).
// LDS: 3 buffers x (A 256x64 + B 128x64) bf16 = 144 KB. Tile t reads buf[t%3],
// tile t+2 stages into buf[(t+2)%3] -> prefetch is race-free without draining vmcnt.
// Loop body: ds_read frags (before stage issue, template order) -> 6x global_load_lds
// -> MFMA under setprio -> s_waitcnt vmcnt(6) lgkmcnt(0) -> raw s_barrier.
// Mainloop swizzle: physical colblk = logical ^ (row&7), staged via swizzled source.
// Block swizzle: bijective XCD-chunked (m204) so an m-stripe's n-tiles share one L2.
// E: 1 +bias->bf16, 2 +bias+res->bf16, 3 gelu->bf16, 4 +bias+res->f32,
//    5 fused qkv: N=1536, cols 0-1023 phi(elu+1), split into 3 consecutive buffers
template <int E>
__launch_bounds__(512, 2)
__global__ void gemm256(const uint16_t* __restrict__ A, const uint16_t* __restrict__ BT,
                        const float* __restrict__ bias, const uint16_t* __restrict__ res,
                        void* __restrict__ outp, int M, int N, int K) {
  __shared__ __align__(16) uint16_t S[3 * 24576];   // 147456 B; epilogue reuses as C tile
  const int tid = threadIdx.x;
  const int lane = tid & 63, wave = tid >> 6;
  const int l15 = lane & 15, l4 = lane >> 4;
  const int wm = (wave >> 1) * 64, wn = (wave & 1) * 64;

  // bijective XCD-chunked block swizzle (HW round-robins linear id across 8 XCDs)
  const int gx = gridDim.x;
  const int nwg = gx * gridDim.y;
  const int orig = blockIdx.y * gx + blockIdx.x;
  const int q = nwg >> 3, r = nwg & 7;
  const int xcd = orig & 7, off = orig >> 3;
  const int tile = (xcd < r ? xcd * (q + 1) : r * (q + 1) + (xcd - r) * q) + off;
  const int tn = tile % gx, tm = tile / gx;
  const int m0 = tm * 256, n0 = tn * 128;

  uint16_t *A0 = S,             *B0 = S + 16384;
  uint16_t *A1 = S + 24576,     *B1 = S + 40960;
  uint16_t *A2 = S + 49152,     *B2 = S + 65536;

  // staging: thread -> (row-in-64-slice, col-block), source col-block pre-swizzled
  const int srow = tid >> 3;                      // 0..63
  const int scb  = (tid & 7) ^ (srow & 7);        // swizzled source col-block
  const uint16_t* ga = A  + (size_t)(m0 + srow) * K + scb * 8;
  const uint16_t* gb = BT + (size_t)(n0 + srow) * K + scb * 8;
  auto stage = [&](uint16_t* Ad, uint16_t* Bd, int kb) {
#pragma unroll
    for (int r2 = 0; r2 < 4; ++r2)                // A: 4 rounds x 64 rows
      cp16(ga + (size_t)r2 * 64 * K + kb, Ad + (r2 * 64 + wave * 8) * 64);
#pragma unroll
    for (int r2 = 0; r2 < 2; ++r2)                // B: 2 rounds x 64 rows
      cp16(gb + (size_t)r2 * 64 * K + kb, Bd + (r2 * 64 + wave * 8) * 64);
  };

  f32x4 acc[4][4];
#pragma unroll
  for (int i = 0; i < 4; ++i)
#pragma unroll
    for (int j = 0; j < 4; ++j) acc[i][j] = (f32x4){0.f, 0.f, 0.f, 0.f};

  const int NT = K >> 6;
  stage(A0, B0, 0);
  stage(A1, B1, 64);
  asm volatile("s_waitcnt vmcnt(6)" ::: "memory");   // stage(0) landed
  __builtin_amdgcn_s_barrier();
  asm volatile("" ::: "memory");

  for (int t = 0; t < NT; ++t) {
    // frag ds_reads FIRST (template order: reads precede this tile's stage issue)
    short8 af[2][4], bfr[2][4];
#pragma unroll
    for (int h = 0; h < 2; ++h) {                 // h = kk/32
#pragma unroll
      for (int i = 0; i < 4; ++i)
        af[h][i] = *(const short8*)&A0[(wm + i * 16 + l15) * 64 +
                                       (((h * 4 + l4) ^ (l15 & 7)) * 8)];
#pragma unroll
      for (int j = 0; j < 4; ++j)
        bfr[h][j] = *(const short8*)&B0[(wn + j * 16 + l15) * 64 +
                                        (((h * 4 + l4) ^ (l15 & 7)) * 8)];
    }
    if (t + 2 < NT) stage(A2, B2, (t + 2) << 6);  // prefetch 2 tiles ahead
#pragma unroll
    for (int h = 0; h < 2; ++h) {
      __builtin_amdgcn_s_setprio(1);
#pragma unroll
      for (int i = 0; i < 4; ++i)
#pragma unroll
        for (int j = 0; j < 4; ++j)
          acc[i][j] = __builtin_amdgcn_mfma_f32_16x16x32_bf16(af[h][i], bfr[h][j],
                                                              acc[i][j], 0, 0, 0);
      __builtin_amdgcn_s_setprio(0);
    }
    // counted wait: stage(t+1) landed, stage(t+2) (6 loads) stays in flight
    if (t + 2 < NT) asm volatile("s_waitcnt vmcnt(6) lgkmcnt(0)" ::: "memory");
    else            asm volatile("s_waitcnt vmcnt(0) lgkmcnt(0)" ::: "memory");
    __builtin_amdgcn_s_barrier();
    asm volatile("" ::: "memory");
    uint16_t* tA = A0; A0 = A1; A1 = A2; A2 = tA;
    uint16_t* tB = B0; B0 = B1; B1 = B2; B2 = tB;
  }

  // ---- epilogue phase 1: bias+activation in fragment layout -> swizzled LDS (bf16)
#pragma unroll
  for (int i = 0; i < 4; ++i)
#pragma unroll
    for (int rg = 0; rg < 4; ++rg) {
      const int lrow = wm + i * 16 + l4 * 4 + rg;  // C/D: row = quad*4+reg
#pragma unroll
      for (int j = 0; j < 4; ++j) {
        const int lcol = wn + j * 16 + l15;        // C/D: col = lane&15
        float v = acc[i][j][rg] + bias[n0 + lcol];
        if (E == 5) {
          if (n0 + lcol < 1024) v = v > 0.f ? v + 1.f : __expf(v);  // phi = elu+1
        } else if (E == 3) {
          v = gelu_f(v);
        }
        S[lrow * 128 + ((((lcol >> 3) ^ (lrow >> 2)) & 15) * 8) + (lcol & 7)] = f2bf(v);
      }
    }
  __syncthreads();

  // ---- epilogue phase 2: coalesced readback + residual + store (16B/lane)
  uint16_t* outb = (uint16_t*)outp;
  float* outf = (float*)outp;
  const int rr = tid >> 4;          // row within 32-row pass
  const int cb = tid & 15;          // 16B col-block
#pragma unroll
  for (int p = 0; p < 8; ++p) {
    const int lrow = p * 32 + rr;
    const int row = m0 + lrow;
    const int col0 = n0 + cb * 8;
    const uint4 d = *(const uint4*)&S[lrow * 128 + ((cb ^ (lrow >> 2)) & 15) * 8];
    if (E == 5) {
      const size_t offs = (size_t)(col0 >> 9) * ((size_t)ROWST * DD) +
                          (size_t)row * DD + (col0 & 511);
      *(uint4*)&outb[offs] = d;
    } else if (E == 1 || E == 3) {
      *(uint4*)&outb[(size_t)row * N + col0] = d;
    } else {
      const size_t idx = (size_t)row * N + col0;
      const uint4 rd = *(const uint4*)&res[idx];
      float a[8];
      a[0] = bf2f((uint16_t)(d.x & 0xffff)) + bf2f((uint16_t)(rd.x & 0xffff));
      a[1] = bf2f((uint16_t)(d.x >> 16))    + bf2f((uint16_t)(rd.x >> 16));
      a[2] = bf2f((uint16_t)(d.y & 0xffff)) + bf2f((uint16_t)(rd.y & 0xffff));
      a[3] = bf2f((uint16_t)(d.y >> 16))    + bf2f((uint16_t)(rd.y >> 16));
      a[4] = bf2f((uint16_t)(d.z & 0xffff)) + bf2f((uint16_t)(rd.z & 0xffff));
      a[5] = bf2f((uint16_t)(d.z >> 16))    + bf2f((uint16_t)(rd.z >> 16));
      a[6] = bf2f((uint16_t)(d.w & 0xffff)) + bf2f((uint16_t)(rd.w & 0xffff));
      a[7] = bf2f((uint16_t)(d.w >> 16))    + bf2f((uint16_t)(rd.w >> 16));
      if (E == 2) {
        uint4 o;
        o.x = (uint32_t)f2bf(a[0]) | ((uint32_t)f2bf(a[1]) << 16);
        o.y = (uint32_t)f2bf(a[2]) | ((uint32_t)f2bf(a[3]) << 16);
        o.z = (uint32_t)f2bf(a[4]) | ((uint32_t)f2bf(a[5]) << 16);
        o.w = (uint32_t)f2bf(a[6]) | ((uint32_t)f2bf(a[7]) << 16);
        *(uint4*)&outb[idx] = o;
      } else {                       // E == 4: f32 out
        *(float4*)&outf[idx]     = (float4){a[0], a[1], a[2], a[3]};
        *(float4*)&outf[idx + 4] = (float4){a[4], a[5], a[6], a[7]};
      }
    }
  }
}

// ---------------- LayerNorm: one wave per 512-elem row, out bf16 ----------------
template <int BFIN>
__launch_bounds__(256)
__global__ void ln_kernel(const void* __restrict__ inp, const float* __restrict__ gam,
                          const float* __restrict__ bet, uint16_t* __restrict__ out) {
  const int row = blockIdx.x * 4 + (threadIdx.x >> 6);
  const int lane = threadIdx.x & 63;
  const size_t base = (size_t)row * DD + lane * 8;
  float x[8];
  if (BFIN) {
    const uint4 u = *(const uint4*)((const uint16_t*)inp + base);
    x[0] = bf2f((uint16_t)(u.x & 0xffff)); x[1] = bf2f((uint16_t)(u.x >> 16));
    x[2] = bf2f((uint16_t)(u.y & 0xffff)); x[3] = bf2f((uint16_t)(u.y >> 16));
    x[4] = bf2f((uint16_t)(u.z & 0xffff)); x[5] = bf2f((uint16_t)(u.z >> 16));
    x[6] = bf2f((uint16_t)(u.w & 0xffff)); x[7] = bf2f((uint16_t)(u.w >> 16));
  } else {
    const float* f = (const float*)inp + base;
    const float4 a = *(const float4*)f;
    const float4 b = *(const float4*)(f + 4);
    x[0]=a.x; x[1]=a.y; x[2]=a.z; x[3]=a.w; x[4]=b.x; x[5]=b.y; x[6]=b.z; x[7]=b.w;
  }
  float s = 0.f, s2 = 0.f;
#pragma unroll
  for (int j = 0; j < 8; ++j) { s += x[j]; s2 += x[j] * x[j]; }
#pragma unroll
  for (int off = 32; off; off >>= 1) { s += __shfl_xor(s, off, 64); s2 += __shfl_xor(s2, off, 64); }
  const float m = s * (1.f / DD);
  const float rs = rsqrtf(s2 * (1.f / DD) - m * m + 1e-5f);
  uint16_t o[8];
#pragma unroll
  for (int j = 0; j < 8; ++j) {
    const int col = lane * 8 + j;
    o[j] = f2bf((x[j] - m) * rs * gam[col] + bet[col]);
  }
  uint4 w;
  w.x = (uint32_t)o[0] | ((uint32_t)o[1] << 16);
  w.y = (uint32_t)o[2] | ((uint32_t)o[3] << 16);
  w.z = (uint32_t)o[4] | ((uint32_t)o[5] << 16);
  w.w = (uint32_t)o[6] | ((uint32_t)o[7] << 16);
  *(uint4*)(out + base) = w;
}

// ---------------- weight transpose fp32[R,C] -> bf16[C,R] ----------------
__launch_bounds__(256)
__global__ void transpose_bf(const float* __restrict__ in, uint16_t* __restrict__ out,
                             int R, int C) {
  __shared__ float tile[32][33];
  const int tx = threadIdx.x, ty = threadIdx.y;
  const int c0 = blockIdx.x * 32, r0 = blockIdx.y * 32;
#pragma unroll
  for (int i = 0; i < 32; i += 8)
    tile[ty + i][tx] = in[(size_t)(r0 + ty + i) * C + (c0 + tx)];
  __syncthreads();
#pragma unroll
  for (int i = 0; i < 32; i += 8)
    out[(size_t)(c0 + ty + i) * R + (r0 + tx)] = f2bf(tile[tx][ty + i]);
}

__global__ void concat_bias(const float* __restrict__ bq, const float* __restrict__ bk,
                            const float* __restrict__ bv, float* __restrict__ o) {
  const int t = blockIdx.x * 256 + threadIdx.x;
  if (t < 512) o[t] = bq[t];
  else if (t < 1024) o[t] = bk[t - 512];
  else if (t < 1536) o[t] = bv[t - 1024];
}

// ---------------- kv partials via MFMA: kv[b,h,dk,dv] = sum_n pk*v ----------------
__launch_bounds__(256)
__global__ void kv_mfma(const uint16_t* __restrict__ pk, const uint16_t* __restrict__ v,
                        float* __restrict__ kvp, float* __restrict__ ksp) {
  __shared__ __align__(16) uint16_t sT[4][2][64 * 64];  // [wave][pk|v][swizzled]
  __shared__ float ksred[64];
  const int bh = blockIdx.x, b = bh >> 3, h = bh & 7;
  const int t = threadIdx.x, lane = t & 63, w = t >> 6;
  const int l15 = lane & 15, l4 = lane >> 4;
  if (t < 64) ksred[t] = 0.f;
  __syncthreads();

  f32x4 acc[4][4];
#pragma unroll
  for (int i = 0; i < 4; ++i)
#pragma unroll
    for (int j = 0; j < 4; ++j) acc[i][j] = (f32x4){0.f, 0.f, 0.f, 0.f};
  float ks[4] = {0.f, 0.f, 0.f, 0.f};

  const int rl = lane >> 3, cl = (lane & 7) * 8;  // load: 8 rows x 64 cols per round
  for (int sc = 0; sc < 4; ++sc) {
    const int nbase = blockIdx.y * 1024 + w * 256 + sc * 64;
#pragma unroll
    for (int ro = 0; ro < 8; ++ro) {
      const int n = ro * 8 + rl;
      const size_t gofs = ((size_t)(b * NN + nbase + n) * HH + h) * 64 + cl;
      const short8 pv = *(const short8*)(pk + gofs);
      const short8 vv = *(const short8*)(v + gofs);
#pragma unroll
      for (int j = 0; j < 8; ++j) {           // transpose into [dk][n] / [dv][n]
        sT[w][0][swz(cl + j, n)] = (uint16_t)pv[j];
        sT[w][1][swz(cl + j, n)] = (uint16_t)vv[j];
      }
    }
#pragma unroll
    for (int kk = 0; kk < 64; kk += 32) {
      short8 af[4], bfr[4];
#pragma unroll
      for (int i = 0; i < 4; ++i)
        af[i] = *(const short8*)&sT[w][0][swz(i * 16 + l15, kk + l4 * 8)];
#pragma unroll
      for (int j = 0; j < 4; ++j)
        bfr[j] = *(const short8*)&sT[w][1][swz(j * 16 + l15, kk + l4 * 8)];
#pragma unroll
      for (int i = 0; i < 4; ++i) {
#pragma unroll
        for (int e = 0; e < 8; ++e) ks[i] += bf2f((uint16_t)af[i][e]);
#pragma unroll
        for (int j = 0; j < 4; ++j)
          acc[i][j] = __builtin_amdgcn_mfma_f32_16x16x32_bf16(af[i], bfr[j], acc[i][j], 0, 0, 0);
      }
    }
  }
#pragma unroll
  for (int i = 0; i < 4; ++i) {
    float s = ks[i];
    s += __shfl_xor(s, 16, 64); s += __shfl_xor(s, 32, 64);
    if (l4 == 0) atomicAdd(&ksred[i * 16 + l15], s);
  }
  __syncthreads();
  float* red = (float*)&sT[0][0][0];
  if (w > 0) {
#pragma unroll
    for (int i = 0; i < 4; ++i)
#pragma unroll
      for (int r = 0; r < 4; ++r)
#pragma unroll
        for (int j = 0; j < 4; ++j)
          red[(w - 1) * 4096 + (i * 16 + l4 * 4 + r) * 64 + j * 16 + l15] = acc[i][j][r];
  }
  __syncthreads();
  if (w == 0) {
    float* dst = kvp + ((size_t)bh * 16 + blockIdx.y) * 4096;
#pragma unroll
    for (int i = 0; i < 4; ++i)
#pragma unroll
      for (int r = 0; r < 4; ++r)
#pragma unroll
        for (int j = 0; j < 4; ++j) {
          const int e = (i * 16 + l4 * 4 + r) * 64 + j * 16 + l15;
          dst[e] = acc[i][j][r] + red[e] + red[4096 + e] + red[8192 + e];
        }
  }
  if (t < 64) ksp[((size_t)bh * 16 + blockIdx.y) * 64 + t] = ksred[t];
}

// sum the 16 per-chunk partials. grid (32, 17): y==16 handles ksum.
__launch_bounds__(256)
__global__ void kv_reduce(const float* __restrict__ kvp, const float* __restrict__ ksp,
                          float* __restrict__ kv, float* __restrict__ ksum) {
  const int bh = blockIdx.x;
  if (blockIdx.y == 16) {
    if (threadIdx.x < 64) {
      float s = 0.f;
      for (int c = 0; c < 16; ++c) s += ksp[((size_t)bh * 16 + c) * 64 + threadIdx.x];
      ksum[bh * 64 + threadIdx.x] = s;
    }
    return;
  }
  const int e = blockIdx.y * 256 + threadIdx.x;
  float s = 0.f;
  for (int c = 0; c < 16; ++c) s += kvp[((size_t)bh * 16 + c) * 4096 + e];
  kv[(size_t)bh * 4096 + e] = s;
}

// ---------------- attn via MFMA: attn = (pq @ kv) / (pq . ksum + eps) ----------------
__launch_bounds__(256)
__global__ void attn_mfma(const uint16_t* __restrict__ pq, const float* __restrict__ kv,
                          const float* __restrict__ ksum, uint16_t* __restrict__ attn) {
  __shared__ __align__(16) uint16_t kvT[64 * 64];   // B: [dv][dk] swizzled, bf16
  __shared__ float ksS[64];
  __shared__ float denS[4][64];
  const int bh = blockIdx.x, b = bh >> 3, h = bh & 7;
  const int t = threadIdx.x, lane = t & 63, w = t >> 6;
  const int l15 = lane & 15, l4 = lane >> 4;
  const float* kvb = kv + (size_t)bh * 4096;
#pragma unroll
  for (int u = 0; u < 16; ++u) {
    const int e = u * 256 + t;                       // e = dk*64 + dv
    kvT[swz(e & 63, e >> 6)] = f2bf(kvb[e]);
  }
  if (t < 64) ksS[t] = ksum[bh * 64 + t];
  __syncthreads();

  float ksr[16];
#pragma unroll
  for (int kk2 = 0; kk2 < 2; ++kk2) {
    const float4 k0 = *(const float4*)&ksS[kk2 * 32 + l4 * 8];
    const float4 k1 = *(const float4*)&ksS[kk2 * 32 + l4 * 8 + 4];
    ksr[kk2 * 8 + 0] = k0.x; ksr[kk2 * 8 + 1] = k0.y; ksr[kk2 * 8 + 2] = k0.z; ksr[kk2 * 8 + 3] = k0.w;
    ksr[kk2 * 8 + 4] = k1.x; ksr[kk2 * 8 + 5] = k1.y; ksr[kk2 * 8 + 6] = k1.z; ksr[kk2 * 8 + 7] = k1.w;
  }
  short8 bfrg[2][4];
#pragma unroll
  for (int kk2 = 0; kk2 < 2; ++kk2)
#pragma unroll
    for (int j = 0; j < 4; ++j)
      bfrg[kk2][j] = *(const short8*)&kvT[swz(j * 16 + l15, kk2 * 32 + l4 * 8)];

  const int n0w = blockIdx.y * 256 + w * 64;
  f32x4 acc[4][4];
#pragma unroll
  for (int i = 0; i < 4; ++i)
#pragma unroll
    for (int j = 0; j < 4; ++j) acc[i][j] = (f32x4){0.f, 0.f, 0.f, 0.f};
  float den[4] = {0.f, 0.f, 0.f, 0.f};

#pragma unroll
  for (int i = 0; i < 4; ++i) {
    const int n = n0w + i * 16 + l15;
    const size_t abase = ((size_t)(b * NN + n) * HH + h) * 64 + l4 * 8;
#pragma unroll
    for (int kk2 = 0; kk2 < 2; ++kk2) {
      const short8 af = *(const short8*)(pq + abase + kk2 * 32);
#pragma unroll
      for (int e = 0; e < 8; ++e) den[i] += bf2f((uint16_t)af[e]) * ksr[kk2 * 8 + e];
#pragma unroll
      for (int j = 0; j < 4; ++j)
        acc[i][j] = __builtin_amdgcn_mfma_f32_16x16x32_bf16(af, bfrg[kk2][j], acc[i][j], 0, 0, 0);
    }
  }
#pragma unroll
  for (int i = 0; i < 4; ++i) {
    float s = den[i];
    s += __shfl_xor(s, 16, 64); s += __shfl_xor(s, 32, 64);
    if (l4 == 0) denS[w][i * 16 + l15] = s;          // same-wave LDS, in-order
  }
#pragma unroll
  for (int i = 0; i < 4; ++i)
#pragma unroll
    for (int r = 0; r < 4; ++r) {
      const float z = 1.f / (denS[w][i * 16 + l4 * 4 + r] + 1e-6f);
      const int n = n0w + i * 16 + l4 * 4 + r;
      const size_t ob = ((size_t)(b * NN + n) * HH + h) * 64;
#pragma unroll
      for (int j = 0; j < 4; ++j)
        attn[ob + j * 16 + l15] = f2bf(acc[i][j][r] * z);
    }
}

// ---------------- host launch ----------------
extern "C" void kernel_launch(void* const* d_in, const int* in_sizes, int n_in,
                              void* d_out, int out_size, void* d_ws, size_t ws_size,
                              hipStream_t stream) {
  (void)in_sizes; (void)n_in; (void)out_size;
  const float* x    = (const float*)d_in[0];
  const float* ln1g = (const float*)d_in[1];
  const float* ln1b = (const float*)d_in[2];
  const float* Wq   = (const float*)d_in[3];
  const float* bq   = (const float*)d_in[4];
  const float* Wk   = (const float*)d_in[5];
  const float* bk   = (const float*)d_in[6];
  const float* Wv   = (const float*)d_in[7];
  const float* bv   = (const float*)d_in[8];
  const float* Wo   = (const float*)d_in[9];
  const float* bo   = (const float*)d_in[10];
  const float* ln2g = (const float*)d_in[11];
  const float* ln2b = (const float*)d_in[12];
  const float* W1   = (const float*)d_in[13];
  const float* b1   = (const float*)d_in[14];
  const float* W2   = (const float*)d_in[15];
  const float* b2   = (const float*)d_in[16];

  if (ws_size < 409000000ULL) return;

  char* p = (char*)d_ws;
  auto alloc = [&](size_t bytes) -> char* {
    char* r = p; p += (bytes + 255) & ~(size_t)255; return r;
  };
  uint16_t* Hb  = (uint16_t*)alloc((size_t)ROWST * DD * 2);   // h (LN1 out)
  uint16_t* PQ  = (uint16_t*)alloc((size_t)ROWST * DD * 2);   // phi(q); later h2
  uint16_t* PK  = (uint16_t*)alloc((size_t)ROWST * DD * 2);   // phi(k); later hres
  uint16_t* PV  = (uint16_t*)alloc((size_t)ROWST * DD * 2);   // v; later attn
  uint16_t* U   = (uint16_t*)alloc((size_t)32768 * HIDN * 2); // MLP hidden chunk (also kv scratch)
  uint16_t* WqkvT = (uint16_t*)alloc((size_t)1536 * DD * 2);
  uint16_t* WoT = (uint16_t*)alloc((size_t)DD * DD * 2);
  uint16_t* W1T = (uint16_t*)alloc((size_t)HIDN * DD * 2);
  uint16_t* W2T = (uint16_t*)alloc((size_t)DD * HIDN * 2);
  float*    bqkv = (float*)alloc(1536 * 4);
  float* KVP = (float*)U;                  // 512*4096 fp32 = 8 MiB
  float* KSP = KVP + 512 * 4096;           // 512*64 fp32
  float* KV  = KSP + 512 * 64;             // 32*4096 fp32
  float* KS  = KV + 32 * 4096;             // 32*64 fp32

  const dim3 tb(32, 8);
  transpose_bf<<<dim3(16, 16), tb, 0, stream>>>(Wq, WqkvT, DD, DD);
  transpose_bf<<<dim3(16, 16), tb, 0, stream>>>(Wk, WqkvT + 512 * 512, DD, DD);
  transpose_bf<<<dim3(16, 16), tb, 0, stream>>>(Wv, WqkvT + 2 * 512 * 512, DD, DD);
  transpose_bf<<<dim3(16, 16), tb, 0, stream>>>(Wo, WoT, DD, DD);
  transpose_bf<<<dim3(64, 16), tb, 0, stream>>>(W1, W1T, DD, HIDN);
  transpose_bf<<<dim3(16, 64), tb, 0, stream>>>(W2, W2T, HIDN, DD);
  concat_bias<<<6, 256, 0, stream>>>(bq, bk, bv, bqkv);

  // h = LN1(x)
  ln_kernel<0><<<ROWST / 4, 256, 0, stream>>>(x, ln1g, ln1b, Hb);
  // fused qkv: [pq|pk|v] = epi(h @ Wqkv + b)
  gemm256<5><<<dim3(12, 256), 512, 0, stream>>>(Hb, WqkvT, bqkv, nullptr, PQ, ROWST, 1536, DD);
  // kv / ksum via MFMA partials + reduce
  kv_mfma<<<dim3(32, 16), 256, 0, stream>>>(PK, PV, KVP, KSP);
  kv_reduce<<<dim3(32, 17), 256, 0, stream>>>(KVP, KSP, KV, KS);
  // attn (normalized) -> PV
  attn_mfma<<<dim3(32, 64), 256, 0, stream>>>(PQ, KV, KS, PV);
  // hres = attn@Wo + bo + h -> PK
  gemm256<2><<<dim3(4, 256), 512, 0, stream>>>(PV, WoT, bo, Hb, PK, ROWST, DD, DD);
  // h2 = LN2(hres) -> PQ
  ln_kernel<1><<<ROWST / 4, 256, 0, stream>>>(PK, ln2g, ln2b, PQ);
  // MLP in 2 row-chunks: out = h2 + gelu(h2@W1+b1)@W2 + b2
  for (int c = 0; c < 2; ++c) {
    const uint16_t* h2c = PQ + (size_t)c * 32768 * DD;
    gemm256<3><<<dim3(16, 128), 512, 0, stream>>>(h2c, W1T, b1, nullptr, U, 32768, HIDN, DD);
    gemm256<4><<<dim3(4, 128), 512, 0, stream>>>(U, W2T, b2, h2c,
        (float*)d_out + (size_t)c * 32768 * DD, 32768, DD, HIDN);
  }
}

// Round 2
// 959.194 us; speedup vs baseline: 1.0815x; 1.0217x over previous
//
#include <hip/hip_runtime.h>
#include <stdint.h>

// Problem constants
#define BB   4
#define NN   16384
#define HH   8
#define DD   512
#define HIDN 2048
#define ROWST (BB * NN)   // 65536 token rows

using short8 = __attribute__((ext_vector_type(8))) short;   // 8 bf16 (4 VGPRs)
using f32x4  = __attribute__((ext_vector_type(4))) float;   // MFMA acc

__device__ __forceinline__ float bf2f(uint16_t h) {
  union { uint32_t u; float f; } v; v.u = ((uint32_t)h) << 16; return v.f;
}
__device__ __forceinline__ uint16_t f2bf(float f) {
  union { float f; uint32_t u; } v; v.f = f;
  return (uint16_t)((v.u + 0x7FFFu + ((v.u >> 16) & 1u)) >> 16);  // RNE
}
// gelu tanh-approx via sigmoid identity
__device__ __forceinline__ float gelu_f(float x) {
  const float t1 = x * x;
  const float inner = __builtin_fmaf(0.044715f * t1, x, x);  // x + 0.044715x^3
  const float e = __expf(-1.5957691216f * inner);            // exp(-2u)
  return x * __builtin_amdgcn_rcpf(1.f + e);
}
// async global->LDS, 16B/lane; LDS dest = wave-uniform base + lane*16
__device__ __forceinline__ void cp16(const uint16_t* g, uint16_t* l) {
  __builtin_amdgcn_global_load_lds((const __attribute__((address_space(1))) void*)g,
                                   (__attribute__((address_space(3))) void*)l, 16, 0, 0);
}
// XOR-swizzled LDS index for transposed [row][64] bf16 tiles (kv/attn kernels).
__device__ __forceinline__ int swz(int row, int col) {
  return row * 64 + (col ^ (row & 56));
}

// ---------------- GEMM 256x256 tile, BK=64, m201-style 4-phase/tile pipeline ----------
// C[M,N] = A[M,K](bf16) * B^T[N,K](bf16) + epilogue.
// 512 threads = 8 waves as 2(m) x 4(n); per-wave output 128x64 (8x4 16x16 frags).
// LDS: 2 bufs x (A 256x64 + B 256x64) bf16 = 128 KB, managed at K-HALF granularity:
// each K-tile = 4 half-tiles {A-k0, A-k1, B-k0, B-k1}, 16 KB each, stored as
// [128 row-pair][8 phys 16B-block] with pb = ((row&1)*4 + kcb) ^ (rp&7) swizzle
// (conflict-free ds_read_b128; staged via pre-swizzled per-lane global source,
// linear LDS dest as global_load_lds requires).
// Per tile: 4 phases {ds_read frags | stage 1 half | barrier | lgkmcnt(0) |
// setprio(1) 16 MFMA setprio(0) | [p4: vmcnt(4)] | barrier}. vmcnt never drains
// to 0 in steady state: (t+2).A0/B0 ride across each tile boundary into the k0
// region released at end of p2. Ledger:
//   p1 stage (t+1).A1 -> NXT k1 (reads closed end of tile t-1)       [2 loads]
//   p2 stage (t+1).B1 -> NXT k1                                      [2 loads]
//   p3 stage (t+2).A0 -> CUR k0 (k0 reads closed at end of p2)       [2 loads]
//   p4 stage (t+2).B0 -> CUR k0; vmcnt(4) leaves exactly those 4 in flight,
//      guaranteeing tile t+1 fully landed before its p1.
// E: 2 +bias+res->bf16, 3 gelu->bf16, 4 +bias+res->f32,
//    5 fused qkv: N=1536, cols 0-1023 phi(elu+1), split into 3 consecutive buffers
template <int E>
__launch_bounds__(512, 2)
__global__ void gemm256(const uint16_t* __restrict__ A, const uint16_t* __restrict__ BT,
                        const float* __restrict__ bias, const uint16_t* __restrict__ res,
                        void* __restrict__ outp, int M, int N, int K) {
  __shared__ __align__(16) uint16_t S[65536];   // 128 KB; epilogue reuses as C 256x256
  const int tid = threadIdx.x;
  const int lane = tid & 63, wave = tid >> 6;
  const int l15 = lane & 15, l4 = lane >> 4;
  const int wm = (wave >> 2) * 128, wn = (wave & 3) * 64;   // 2m x 4n waves

  // bijective XCD-chunked block swizzle (all grids have nwg % 8 == 0)
  const int gx = gridDim.x;
  const int nwg = gx * gridDim.y;
  const int orig = blockIdx.y * gx + blockIdx.x;
  const int cpx = nwg >> 3;
  const int tile = (orig & 7) * cpx + (orig >> 3);
  const int tn = tile % gx, tm = tile / gx;
  const int m0 = tm * 256, n0 = tn * 256;

  // staging: slot s = r2*512 + tid -> rp = s>>3, pb = s&7; unswizzle to source
  const int bsw = (tid & 7) ^ ((tid >> 3) & 7);
  const int row_lo = ((tid >> 3) << 1) + (bsw >> 2);   // 0..127
  const int c8 = (bsw & 3) * 8;
  const uint16_t* pA = A  + (size_t)(m0 + row_lo) * K + c8;
  const uint16_t* pB = BT + (size_t)(n0 + row_lo) * K + c8;
  const size_t rstep = (size_t)128 * K;
  const int dstw = wave * 512;                 // u16: wave*64 slots * 8

  // frag read bases (u16): half-region + rp*64 + pb*8
  const int pbF = (((l15 & 1) << 2) | l4) ^ (l15 >> 1);
  const int abase = wm * 32 + (l15 >> 1) * 64 + pbF * 8;            // +MH*2048+f*512
  const int bbase = 16384 + wn * 32 + (l15 >> 1) * 64 + pbF * 8;    // +j*512

  auto stageA = [&](int buf, int kh, int kb) {   // one 16KB half: 2 cp16/thread
    uint16_t* d = S + buf * 32768 + kh * 8192 + dstw;
    const uint16_t* s = pA + kb + kh * 32;
    cp16(s, d);
    cp16(s + rstep, d + 4096);
  };
  auto stageB = [&](int buf, int kh, int kb) {
    uint16_t* d = S + buf * 32768 + 16384 + kh * 8192 + dstw;
    const uint16_t* s = pB + kb + kh * 32;
    cp16(s, d);
    cp16(s + rstep, d + 4096);
  };

  f32x4 acc[8][4];
#pragma unroll
  for (int i = 0; i < 8; ++i)
#pragma unroll
    for (int j = 0; j < 4; ++j) acc[i][j] = (f32x4){0.f, 0.f, 0.f, 0.f};
  short8 bf[4];

  const int NT = K >> 6;                       // 8 or 32, always even
  // prologue: tile0 fully, tile1 k0; wait tile0 landed, keep tile1.k0 in flight
  stageA(0, 0, 0);  stageB(0, 0, 0);
  stageA(0, 1, 0);  stageB(0, 1, 0);
  stageA(1, 0, 64); stageB(1, 0, 64);
  asm volatile("s_waitcnt vmcnt(4)" ::: "memory");
  __builtin_amdgcn_s_barrier();
  asm volatile("" ::: "memory");

#define PHASE(BUF, MH, KH, RB, PRE, POST)                                        \
  {                                                                              \
    short8 af[4];                                                                \
    _Pragma("unroll")                                                            \
    for (int f = 0; f < 4; ++f)                                                  \
      af[f] = *(const short8*)&S[(BUF)*32768 + (KH)*8192 + (MH)*2048 + abase + f*512]; \
    if (RB) {                                                                    \
      _Pragma("unroll")                                                          \
      for (int j = 0; j < 4; ++j)                                                \
        bf[j] = *(const short8*)&S[(BUF)*32768 + (KH)*8192 + bbase + j*512];     \
    }                                                                            \
    PRE;                                                                         \
    asm volatile("" ::: "memory");                                               \
    __builtin_amdgcn_s_barrier();                                                \
    asm volatile("s_waitcnt lgkmcnt(0)" ::: "memory");                           \
    __builtin_amdgcn_sched_barrier(0);                                           \
    __builtin_amdgcn_s_setprio(1);                                               \
    _Pragma("unroll")                                                            \
    for (int i = 0; i < 4; ++i)                                                  \
      _Pragma("unroll")                                                          \
      for (int j = 0; j < 4; ++j)                                                \
        acc[(MH)*4 + i][j] = __builtin_amdgcn_mfma_f32_16x16x32_bf16(af[i], bf[j], acc[(MH)*4 + i][j], 0, 0, 0); \
    __builtin_amdgcn_s_setprio(0);                                               \
    __builtin_amdgcn_sched_barrier(0);                                           \
    POST;                                                                        \
    asm volatile("" ::: "memory");                                               \
    __builtin_amdgcn_s_barrier();                                                \
    asm volatile("" ::: "memory");                                               \
  }

  for (int t2 = 0; t2 < NT; t2 += 2) {
    {
      const int t = t2;
      const int kb1 = (t + 1) << 6, kb2 = (t + 2) << 6;
      PHASE(0, 0, 0, 1, if (t + 1 < NT) stageA(1, 1, kb1), {});
      PHASE(0, 1, 0, 0, if (t + 1 < NT) stageB(1, 1, kb1), {});
      PHASE(0, 0, 1, 1, if (t + 2 < NT) stageA(0, 0, kb2), {});
      PHASE(0, 1, 1, 0, if (t + 2 < NT) stageB(0, 0, kb2),
            if (t + 2 < NT) { asm volatile("s_waitcnt vmcnt(4)" ::: "memory"); }
            else            { asm volatile("s_waitcnt vmcnt(0)" ::: "memory"); });
    }
    {
      const int t = t2 + 1;
      const int kb1 = (t + 1) << 6, kb2 = (t + 2) << 6;
      PHASE(1, 0, 0, 1, if (t + 1 < NT) stageA(0, 1, kb1), {});
      PHASE(1, 1, 0, 0, if (t + 1 < NT) stageB(0, 1, kb1), {});
      PHASE(1, 0, 1, 1, if (t + 2 < NT) stageA(1, 0, kb2), {});
      PHASE(1, 1, 1, 0, if (t + 2 < NT) stageB(1, 0, kb2),
            if (t + 2 < NT) { asm volatile("s_waitcnt vmcnt(4)" ::: "memory"); }
            else            { asm volatile("s_waitcnt vmcnt(0)" ::: "memory"); });
    }
  }
#undef PHASE

  // ---- epilogue phase 1: bias+activation in fragment layout -> swizzled LDS (bf16)
  __syncthreads();
  const float bj[4] = {bias[n0 + wn + l15], bias[n0 + wn + 16 + l15],
                       bias[n0 + wn + 32 + l15], bias[n0 + wn + 48 + l15]};
#pragma unroll
  for (int mf = 0; mf < 8; ++mf)
#pragma unroll
    for (int rg = 0; rg < 4; ++rg) {
      const int lrow = wm + mf * 16 + l4 * 4 + rg;   // C/D: row = quad*4+reg
#pragma unroll
      for (int j = 0; j < 4; ++j) {
        const int lcol = wn + j * 16 + l15;          // C/D: col = lane&15
        float v = acc[mf][j][rg] + bj[j];
        if (E == 5) {
          if (n0 + lcol < 1024) v = v > 0.f ? v + 1.f : __expf(v);  // phi = elu+1
        } else if (E == 3) {
          v = gelu_f(v);
        }
        S[lrow * 256 + ((((lcol >> 3) ^ lrow) & 31) * 8) + (lcol & 7)] = f2bf(v);
      }
    }
  __syncthreads();

  // ---- epilogue phase 2: coalesced readback + residual + store (16B/lane)
  uint16_t* outb = (uint16_t*)outp;
  float* outf = (float*)outp;
  const int rr = tid >> 5;          // row within 16-row pass
  const int cb = tid & 31;          // 16B col-block
#pragma unroll
  for (int p = 0; p < 16; ++p) {
    const int lrow = p * 16 + rr;
    const int row = m0 + lrow;
    const int col0 = n0 + cb * 8;
    const uint4 d = *(const uint4*)&S[lrow * 256 + ((cb ^ lrow) & 31) * 8];
    if (E == 5) {
      const size_t offs = (size_t)(col0 >> 9) * ((size_t)ROWST * DD) +
                          (size_t)row * DD + (col0 & 511);
      *(uint4*)&outb[offs] = d;
    } else if (E == 1 || E == 3) {
      *(uint4*)&outb[(size_t)row * N + col0] = d;
    } else {
      const size_t idx = (size_t)row * N + col0;
      const uint4 rd = *(const uint4*)&res[idx];
      float a[8];
      a[0] = bf2f((uint16_t)(d.x & 0xffff)) + bf2f((uint16_t)(rd.x & 0xffff));
      a[1] = bf2f((uint16_t)(d.x >> 16))    + bf2f((uint16_t)(rd.x >> 16));
      a[2] = bf2f((uint16_t)(d.y & 0xffff)) + bf2f((uint16_t)(rd.y & 0xffff));
      a[3] = bf2f((uint16_t)(d.y >> 16))    + bf2f((uint16_t)(rd.y >> 16));
      a[4] = bf2f((uint16_t)(d.z & 0xffff)) + bf2f((uint16_t)(rd.z & 0xffff));
      a[5] = bf2f((uint16_t)(d.z >> 16))    + bf2f((uint16_t)(rd.z >> 16));
      a[6] = bf2f((uint16_t)(d.w & 0xffff)) + bf2f((uint16_t)(rd.w & 0xffff));
      a[7] = bf2f((uint16_t)(d.w >> 16))    + bf2f((uint16_t)(rd.w >> 16));
      if (E == 2) {
        uint4 o;
        o.x = (uint32_t)f2bf(a[0]) | ((uint32_t)f2bf(a[1]) << 16);
        o.y = (uint32_t)f2bf(a[2]) | ((uint32_t)f2bf(a[3]) << 16);
        o.z = (uint32_t)f2bf(a[4]) | ((uint32_t)f2bf(a[5]) << 16);
        o.w = (uint32_t)f2bf(a[6]) | ((uint32_t)f2bf(a[7]) << 16);
        *(uint4*)&outb[idx] = o;
      } else {                       // E == 4: f32 out
        *(float4*)&outf[idx]     = (float4){a[0], a[1], a[2], a[3]};
        *(float4*)&outf[idx + 4] = (float4){a[4], a[5], a[6], a[7]};
      }
    }
  }
}

// ---------------- LayerNorm: one wave per 512-elem row, out bf16 ----------------
template <int BFIN>
__launch_bounds__(256)
__global__ void ln_kernel(const void* __restrict__ inp, const float* __restrict__ gam,
                          const float* __restrict__ bet, uint16_t* __restrict__ out) {
  const int row = blockIdx.x * 4 + (threadIdx.x >> 6);
  const int lane = threadIdx.x & 63;
  const size_t base = (size_t)row * DD + lane * 8;
  float x[8];
  if (BFIN) {
    const uint4 u = *(const uint4*)((const uint16_t*)inp + base);
    x[0] = bf2f((uint16_t)(u.x & 0xffff)); x[1] = bf2f((uint16_t)(u.x >> 16));
    x[2] = bf2f((uint16_t)(u.y & 0xffff)); x[3] = bf2f((uint16_t)(u.y >> 16));
    x[4] = bf2f((uint16_t)(u.z & 0xffff)); x[5] = bf2f((uint16_t)(u.z >> 16));
    x[6] = bf2f((uint16_t)(u.w & 0xffff)); x[7] = bf2f((uint16_t)(u.w >> 16));
  } else {
    const float* f = (const float*)inp + base;
    const float4 a = *(const float4*)f;
    const float4 b = *(const float4*)(f + 4);
    x[0]=a.x; x[1]=a.y; x[2]=a.z; x[3]=a.w; x[4]=b.x; x[5]=b.y; x[6]=b.z; x[7]=b.w;
  }
  float s = 0.f, s2 = 0.f;
#pragma unroll
  for (int j = 0; j < 8; ++j) { s += x[j]; s2 += x[j] * x[j]; }
#pragma unroll
  for (int off = 32; off; off >>= 1) { s += __shfl_xor(s, off, 64); s2 += __shfl_xor(s2, off, 64); }
  const float m = s * (1.f / DD);
  const float rs = rsqrtf(s2 * (1.f / DD) - m * m + 1e-5f);
  uint16_t o[8];
#pragma unroll
  for (int j = 0; j < 8; ++j) {
    const int col = lane * 8 + j;
    o[j] = f2bf((x[j] - m) * rs * gam[col] + bet[col]);
  }
  uint4 w;
  w.x = (uint32_t)o[0] | ((uint32_t)o[1] << 16);
  w.y = (uint32_t)o[2] | ((uint32_t)o[3] << 16);
  w.z = (uint32_t)o[4] | ((uint32_t)o[5] << 16);
  w.w = (uint32_t)o[6] | ((uint32_t)o[7] << 16);
  *(uint4*)(out + base) = w;
}

// ---------------- weight transpose fp32[R,C] -> bf16[C,R] ----------------
__launch_bounds__(256)
__global__ void transpose_bf(const float* __restrict__ in, uint16_t* __restrict__ out,
                             int R, int C) {
  __shared__ float tile[32][33];
  const int tx = threadIdx.x, ty = threadIdx.y;
  const int c0 = blockIdx.x * 32, r0 = blockIdx.y * 32;
#pragma unroll
  for (int i = 0; i < 32; i += 8)
    tile[ty + i][tx] = in[(size_t)(r0 + ty + i) * C + (c0 + tx)];
  __syncthreads();
#pragma unroll
  for (int i = 0; i < 32; i += 8)
    out[(size_t)(c0 + ty + i) * R + (r0 + tx)] = f2bf(tile[tx][ty + i]);
}

__global__ void concat_bias(const float* __restrict__ bq, const float* __restrict__ bk,
                            const float* __restrict__ bv, float* __restrict__ o) {
  const int t = blockIdx.x * 256 + threadIdx.x;
  if (t < 512) o[t] = bq[t];
  else if (t < 1024) o[t] = bk[t - 512];
  else if (t < 1536) o[t] = bv[t - 1024];
}

// ---------------- kv partials via MFMA: kv[b,h,dk,dv] = sum_n pk*v ----------------
__launch_bounds__(256)
__global__ void kv_mfma(const uint16_t* __restrict__ pk, const uint16_t* __restrict__ v,
                        float* __restrict__ kvp, float* __restrict__ ksp) {
  __shared__ __align__(16) uint16_t sT[4][2][64 * 64];  // [wave][pk|v][swizzled]
  __shared__ float ksred[64];
  const int bh = blockIdx.x, b = bh >> 3, h = bh & 7;
  const int t = threadIdx.x, lane = t & 63, w = t >> 6;
  const int l15 = lane & 15, l4 = lane >> 4;
  if (t < 64) ksred[t] = 0.f;
  __syncthreads();

  f32x4 acc[4][4];
#pragma unroll
  for (int i = 0; i < 4; ++i)
#pragma unroll
    for (int j = 0; j < 4; ++j) acc[i][j] = (f32x4){0.f, 0.f, 0.f, 0.f};
  float ks[4] = {0.f, 0.f, 0.f, 0.f};

  const int rl = lane >> 3, cl = (lane & 7) * 8;  // load: 8 rows x 64 cols per round
  for (int sc = 0; sc < 4; ++sc) {
    const int nbase = blockIdx.y * 1024 + w * 256 + sc * 64;
#pragma unroll
    for (int ro = 0; ro < 8; ++ro) {
      const int n = ro * 8 + rl;
      const size_t gofs = ((size_t)(b * NN + nbase + n) * HH + h) * 64 + cl;
      const short8 pv = *(const short8*)(pk + gofs);
      const short8 vv = *(const short8*)(v + gofs);
#pragma unroll
      for (int j = 0; j < 8; ++j) {           // transpose into [dk][n] / [dv][n]
        sT[w][0][swz(cl + j, n)] = (uint16_t)pv[j];
        sT[w][1][swz(cl + j, n)] = (uint16_t)vv[j];
      }
    }
#pragma unroll
    for (int kk = 0; kk < 64; kk += 32) {
      short8 af[4], bfr[4];
#pragma unroll
      for (int i = 0; i < 4; ++i)
        af[i] = *(const short8*)&sT[w][0][swz(i * 16 + l15, kk + l4 * 8)];
#pragma unroll
      for (int j = 0; j < 4; ++j)
        bfr[j] = *(const short8*)&sT[w][1][swz(j * 16 + l15, kk + l4 * 8)];
#pragma unroll
      for (int i = 0; i < 4; ++i) {
#pragma unroll
        for (int e = 0; e < 8; ++e) ks[i] += bf2f((uint16_t)af[i][e]);
#pragma unroll
        for (int j = 0; j < 4; ++j)
          acc[i][j] = __builtin_amdgcn_mfma_f32_16x16x32_bf16(af[i], bfr[j], acc[i][j], 0, 0, 0);
      }
    }
  }
#pragma unroll
  for (int i = 0; i < 4; ++i) {
    float s = ks[i];
    s += __shfl_xor(s, 16, 64); s += __shfl_xor(s, 32, 64);
    if (l4 == 0) atomicAdd(&ksred[i * 16 + l15], s);
  }
  __syncthreads();
  float* red = (float*)&sT[0][0][0];
  if (w > 0) {
#pragma unroll
    for (int i = 0; i < 4; ++i)
#pragma unroll
      for (int r = 0; r < 4; ++r)
#pragma unroll
        for (int j = 0; j < 4; ++j)
          red[(w - 1) * 4096 + (i * 16 + l4 * 4 + r) * 64 + j * 16 + l15] = acc[i][j][r];
  }
  __syncthreads();
  if (w == 0) {
    float* dst = kvp + ((size_t)bh * 16 + blockIdx.y) * 4096;
#pragma unroll
    for (int i = 0; i < 4; ++i)
#pragma unroll
      for (int r = 0; r < 4; ++r)
#pragma unroll
        for (int j = 0; j < 4; ++j) {
          const int e = (i * 16 + l4 * 4 + r) * 64 + j * 16 + l15;
          dst[e] = acc[i][j][r] + red[e] + red[4096 + e] + red[8192 + e];
        }
  }
  if (t < 64) ksp[((size_t)bh * 16 + blockIdx.y) * 64 + t] = ksred[t];
}

// sum the 16 per-chunk partials. grid (32, 17): y==16 handles ksum.
__launch_bounds__(256)
__global__ void kv_reduce(const float* __restrict__ kvp, const float* __restrict__ ksp,
                          float* __restrict__ kv, float* __restrict__ ksum) {
  const int bh = blockIdx.x;
  if (blockIdx.y == 16) {
    if (threadIdx.x < 64) {
      float s = 0.f;
      for (int c = 0; c < 16; ++c) s += ksp[((size_t)bh * 16 + c) * 64 + threadIdx.x];
      ksum[bh * 64 + threadIdx.x] = s;
    }
    return;
  }
  const int e = blockIdx.y * 256 + threadIdx.x;
  float s = 0.f;
  for (int c = 0; c < 16; ++c) s += kvp[((size_t)bh * 16 + c) * 4096 + e];
  kv[(size_t)bh * 4096 + e] = s;
}

// ---------------- attn via MFMA: attn = (pq @ kv) / (pq . ksum + eps) ----------------
__launch_bounds__(256)
__global__ void attn_mfma(const uint16_t* __restrict__ pq, const float* __restrict__ kv,
                          const float* __restrict__ ksum, uint16_t* __restrict__ attn) {
  __shared__ __align__(16) uint16_t kvT[64 * 64];   // B: [dv][dk] swizzled, bf16
  __shared__ float ksS[64];
  __shared__ float denS[4][64];
  const int bh = blockIdx.x, b = bh >> 3, h = bh & 7;
  const int t = threadIdx.x, lane = t & 63, w = t >> 6;
  const int l15 = lane & 15, l4 = lane >> 4;
  const float* kvb = kv + (size_t)bh * 4096;
#pragma unroll
  for (int u = 0; u < 16; ++u) {
    const int e = u * 256 + t;                       // e = dk*64 + dv
    kvT[swz(e & 63, e >> 6)] = f2bf(kvb[e]);
  }
  if (t < 64) ksS[t] = ksum[bh * 64 + t];
  __syncthreads();

  float ksr[16];
#pragma unroll
  for (int kk2 = 0; kk2 < 2; ++kk2) {
    const float4 k0 = *(const float4*)&ksS[kk2 * 32 + l4 * 8];
    const float4 k1 = *(const float4*)&ksS[kk2 * 32 + l4 * 8 + 4];
    ksr[kk2 * 8 + 0] = k0.x; ksr[kk2 * 8 + 1] = k0.y; ksr[kk2 * 8 + 2] = k0.z; ksr[kk2 * 8 + 3] = k0.w;
    ksr[kk2 * 8 + 4] = k1.x; ksr[kk2 * 8 + 5] = k1.y; ksr[kk2 * 8 + 6] = k1.z; ksr[kk2 * 8 + 7] = k1.w;
  }
  short8 bfrg[2][4];
#pragma unroll
  for (int kk2 = 0; kk2 < 2; ++kk2)
#pragma unroll
    for (int j = 0; j < 4; ++j)
      bfrg[kk2][j] = *(const short8*)&kvT[swz(j * 16 + l15, kk2 * 32 + l4 * 8)];

  const int n0w = blockIdx.y * 256 + w * 64;
  f32x4 acc[4][4];
#pragma unroll
  for (int i = 0; i < 4; ++i)
#pragma unroll
    for (int j = 0; j < 4; ++j) acc[i][j] = (f32x4){0.f, 0.f, 0.f, 0.f};
  float den[4] = {0.f, 0.f, 0.f, 0.f};

#pragma unroll
  for (int i = 0; i < 4; ++i) {
    const int n = n0w + i * 16 + l15;
    const size_t abase = ((size_t)(b * NN + n) * HH + h) * 64 + l4 * 8;
#pragma unroll
    for (int kk2 = 0; kk2 < 2; ++kk2) {
      const short8 af = *(const short8*)(pq + abase + kk2 * 32);
#pragma unroll
      for (int e = 0; e < 8; ++e) den[i] += bf2f((uint16_t)af[e]) * ksr[kk2 * 8 + e];
#pragma unroll
      for (int j = 0; j < 4; ++j)
        acc[i][j] = __builtin_amdgcn_mfma_f32_16x16x32_bf16(af, bfrg[kk2][j], acc[i][j], 0, 0, 0);
    }
  }
#pragma unroll
  for (int i = 0; i < 4; ++i) {
    float s = den[i];
    s += __shfl_xor(s, 16, 64); s += __shfl_xor(s, 32, 64);
    if (l4 == 0) denS[w][i * 16 + l15] = s;          // same-wave LDS, in-order
  }
#pragma unroll
  for (int i = 0; i < 4; ++i)
#pragma unroll
    for (int r = 0; r < 4; ++r) {
      const float z = 1.f / (denS[w][i * 16 + l4 * 4 + r] + 1e-6f);
      const int n = n0w + i * 16 + l4 * 4 + r;
      const size_t ob = ((size_t)(b * NN + n) * HH + h) * 64;
#pragma unroll
      for (int j = 0; j < 4; ++j)
        attn[ob + j * 16 + l15] = f2bf(acc[i][j][r] * z);
    }
}

// ---------------- host launch ----------------
extern "C" void kernel_launch(void* const* d_in, const int* in_sizes, int n_in,
                              void* d_out, int out_size, void* d_ws, size_t ws_size,
                              hipStream_t stream) {
  (void)in_sizes; (void)n_in; (void)out_size;
  const float* x    = (const float*)d_in[0];
  const float* ln1g = (const float*)d_in[1];
  const float* ln1b = (const float*)d_in[2];
  const float* Wq   = (const float*)d_in[3];
  const float* bq   = (const float*)d_in[4];
  const float* Wk   = (const float*)d_in[5];
  const float* bk   = (const float*)d_in[6];
  const float* Wv   = (const float*)d_in[7];
  const float* bv   = (const float*)d_in[8];
  const float* Wo   = (const float*)d_in[9];
  const float* bo   = (const float*)d_in[10];
  const float* ln2g = (const float*)d_in[11];
  const float* ln2b = (const float*)d_in[12];
  const float* W1   = (const float*)d_in[13];
  const float* b1   = (const float*)d_in[14];
  const float* W2   = (const float*)d_in[15];
  const float* b2   = (const float*)d_in[16];

  if (ws_size < 409000000ULL) return;

  char* p = (char*)d_ws;
  auto alloc = [&](size_t bytes) -> char* {
    char* r = p; p += (bytes + 255) & ~(size_t)255; return r;
  };
  uint16_t* Hb  = (uint16_t*)alloc((size_t)ROWST * DD * 2);   // h (LN1 out)
  uint16_t* PQ  = (uint16_t*)alloc((size_t)ROWST * DD * 2);   // phi(q); later h2
  uint16_t* PK  = (uint16_t*)alloc((size_t)ROWST * DD * 2);   // phi(k); later hres
  uint16_t* PV  = (uint16_t*)alloc((size_t)ROWST * DD * 2);   // v; later attn
  uint16_t* U   = (uint16_t*)alloc((size_t)32768 * HIDN * 2); // MLP hidden chunk (also kv scratch)
  uint16_t* WqkvT = (uint16_t*)alloc((size_t)1536 * DD * 2);
  uint16_t* WoT = (uint16_t*)alloc((size_t)DD * DD * 2);
  uint16_t* W1T = (uint16_t*)alloc((size_t)HIDN * DD * 2);
  uint16_t* W2T = (uint16_t*)alloc((size_t)DD * HIDN * 2);
  float*    bqkv = (float*)alloc(1536 * 4);
  float* KVP = (float*)U;                  // 512*4096 fp32 = 8 MiB
  float* KSP = KVP + 512 * 4096;           // 512*64 fp32
  float* KV  = KSP + 512 * 64;             // 32*4096 fp32
  float* KS  = KV + 32 * 4096;             // 32*64 fp32

  const dim3 tb(32, 8);
  transpose_bf<<<dim3(16, 16), tb, 0, stream>>>(Wq, WqkvT, DD, DD);
  transpose_bf<<<dim3(16, 16), tb, 0, stream>>>(Wk, WqkvT + 512 * 512, DD, DD);
  transpose_bf<<<dim3(16, 16), tb, 0, stream>>>(Wv, WqkvT + 2 * 512 * 512, DD, DD);
  transpose_bf<<<dim3(16, 16), tb, 0, stream>>>(Wo, WoT, DD, DD);
  transpose_bf<<<dim3(64, 16), tb, 0, stream>>>(W1, W1T, DD, HIDN);
  transpose_bf<<<dim3(16, 64), tb, 0, stream>>>(W2, W2T, HIDN, DD);
  concat_bias<<<6, 256, 0, stream>>>(bq, bk, bv, bqkv);

  // h = LN1(x)
  ln_kernel<0><<<ROWST / 4, 256, 0, stream>>>(x, ln1g, ln1b, Hb);
  // fused qkv: [pq|pk|v] = epi(h @ Wqkv + b)
  gemm256<5><<<dim3(6, 256), 512, 0, stream>>>(Hb, WqkvT, bqkv, nullptr, PQ, ROWST, 1536, DD);
  // kv / ksum via MFMA partials + reduce
  kv_mfma<<<dim3(32, 16), 256, 0, stream>>>(PK, PV, KVP, KSP);
  kv_reduce<<<dim3(32, 17), 256, 0, stream>>>(KVP, KSP, KV, KS);
  // attn (normalized) -> PV
  attn_mfma<<<dim3(32, 64), 256, 0, stream>>>(PQ, KV, KS, PV);
  // hres = attn@Wo + bo + h -> PK
  gemm256<2><<<dim3(2, 256), 512, 0, stream>>>(PV, WoT, bo, Hb, PK, ROWST, DD, DD);
  // h2 = LN2(hres) -> PQ
  ln_kernel<1><<<ROWST / 4, 256, 0, stream>>>(PK, ln2g, ln2b, PQ);
  // MLP in 2 row-chunks: out = h2 + gelu(h2@W1+b1)@W2 + b2
  for (int c = 0; c < 2; ++c) {
    const uint16_t* h2c = PQ + (size_t)c * 32768 * DD;
    gemm256<3><<<dim3(8, 128), 512, 0, stream>>>(h2c, W1T, b1, nullptr, U, 32768, HIDN, DD);
    gemm256<4><<<dim3(2, 128), 512, 0, stream>>>(U, W2T, b2, h2c,
        (float*)d_out + (size_t)c * 32768 * DD, 32768, DD, HIDN);
  }
}

// Round 3
// 957.266 us; speedup vs baseline: 1.0837x; 1.0020x over previous
//
#include <hip/hip_runtime.h>
#include <stdint.h>

// Problem constants
#define BB   4
#define NN   16384
#define HH   8
#define DD   512
#define HIDN 2048
#define ROWST (BB * NN)   // 65536 token rows

using short8 = __attribute__((ext_vector_type(8))) short;   // 8 bf16 (4 VGPRs)
using f32x4  = __attribute__((ext_vector_type(4))) float;   // MFMA acc

__device__ __forceinline__ float bf2f(uint16_t h) {
  union { uint32_t u; float f; } v; v.u = ((uint32_t)h) << 16; return v.f;
}
__device__ __forceinline__ uint16_t f2bf(float f) {
  union { float f; uint32_t u; } v; v.f = f;
  return (uint16_t)((v.u + 0x7FFFu + ((v.u >> 16) & 1u)) >> 16);  // RNE
}
// gelu tanh-approx via sigmoid identity
__device__ __forceinline__ float gelu_f(float x) {
  const float t1 = x * x;
  const float inner = __builtin_fmaf(0.044715f * t1, x, x);  // x + 0.044715x^3
  const float e = __expf(-1.5957691216f * inner);            // exp(-2u)
  return x * __builtin_amdgcn_rcpf(1.f + e);
}
// async global->LDS, 16B/lane; LDS dest = wave-uniform base + lane*16
__device__ __forceinline__ void cp16(const uint16_t* g, uint16_t* l) {
  __builtin_amdgcn_global_load_lds((const __attribute__((address_space(1))) void*)g,
                                   (__attribute__((address_space(3))) void*)l, 16, 0, 0);
}
// XOR-swizzled LDS index for transposed [row][64] bf16 tiles (kv/attn kernels).
__device__ __forceinline__ int swz(int row, int col) {
  return row * 64 + (col ^ (row & 56));
}

// ---------------- GEMM 256x256 tile, BK=64, m201-style 4-phase/tile pipeline ----------
// C[M,N] = A[M,K](bf16) * B^T[N,K](bf16) + epilogue.
// 512 threads = 8 waves as 2(m) x 4(n); per-wave output 128x64 (8x4 16x16 frags).
// LDS: 2 bufs x (A 256x64 + B 256x64) bf16 = 128 KB, K-half granularity.
// KEY (round 3): fragment reads are inline-asm ds_read_b128 (opaque to the
// SIWaitcnt pass). With builtin ds_reads the compiler sees "LDS read aliasing an
// outstanding LDS-DMA" and inserts s_waitcnt vmcnt(0) per phase -> every phase
// eats full HBM latency (round 2: 26% MfmaUtil). Opaque reads leave ONLY the
// hand-placed counted waits: vmcnt(4) once per tile, lgkmcnt(0)+sched_barrier(0)
// per phase (rule #18). No "memory"-clobber asm inside the loop.
// Ledger (per tile t): p1 stage (t+1).A1; p2 stage (t+1).B1; p3 stage (t+2).A0;
// p4 stage (t+2).B0 then vmcnt(4) -> (t+1) fully landed, 4 loads stay in flight.
// E: 2 +bias+res->bf16, 3 gelu->bf16, 4 +bias+res->f32,
//    5 fused qkv: N=1536, cols 0-1023 phi(elu+1), split into 3 consecutive buffers
template <int E>
__launch_bounds__(512, 2)
__global__ void gemm256(const uint16_t* __restrict__ A, const uint16_t* __restrict__ BT,
                        const float* __restrict__ bias, const uint16_t* __restrict__ res,
                        void* __restrict__ outp, int M, int N, int K) {
  __shared__ __align__(16) uint16_t S[65536];   // 128 KB; epilogue reuses as C 256x256
  const int tid = threadIdx.x;
  const int lane = tid & 63, wave = tid >> 6;
  const int l15 = lane & 15, l4 = lane >> 4;
  const int wm = (wave >> 2) * 128, wn = (wave & 3) * 64;   // 2m x 4n waves

  // bijective XCD-chunked block swizzle (all grids have nwg % 8 == 0)
  const int gx = gridDim.x;
  const int nwg = gx * gridDim.y;
  const int orig = blockIdx.y * gx + blockIdx.x;
  const int cpx = nwg >> 3;
  const int tile = (orig & 7) * cpx + (orig >> 3);
  const int tn = tile % gx, tm = tile / gx;
  const int m0 = tm * 256, n0 = tn * 256;

  // staging: slot s = r2*512 + tid -> rp = s>>3, pb = s&7; unswizzle to source
  const int bsw = (tid & 7) ^ ((tid >> 3) & 7);
  const int row_lo = ((tid >> 3) << 1) + (bsw >> 2);   // 0..127
  const int c8 = (bsw & 3) * 8;
  const uint16_t* pA = A  + (size_t)(m0 + row_lo) * K + c8;
  const uint16_t* pB = BT + (size_t)(n0 + row_lo) * K + c8;
  const size_t rstep = (size_t)128 * K;
  const int dstw = wave * 512;                 // u16: wave*64 slots * 8

  // frag read base byte-offsets in LDS (AS3 offset); static part goes in offset:
  const int pbF = (((l15 & 1) << 2) | l4) ^ (l15 >> 1);
  const uint32_t sbase = (uint32_t)(uintptr_t)(__attribute__((address_space(3))) void*)S;
  const uint32_t aoff = sbase + (uint32_t)((wm * 32 + (l15 >> 1) * 64 + pbF * 8) * 2);
  const uint32_t boff = sbase + (uint32_t)((16384 + wn * 32 + (l15 >> 1) * 64 + pbF * 8) * 2);
  const uint32_t aB0_ = aoff,          aB1_ = aoff + 65536;
  const uint32_t bB0_ = boff,          bB1_ = boff + 65536;

  auto stageA = [&](int buf, int kh, int kb) {   // one 16KB half: 2 cp16/thread
    uint16_t* d = S + buf * 32768 + kh * 8192 + dstw;
    const uint16_t* s = pA + kb + kh * 32;
    cp16(s, d);
    cp16(s + rstep, d + 4096);
  };
  auto stageB = [&](int buf, int kh, int kb) {
    uint16_t* d = S + buf * 32768 + 16384 + kh * 8192 + dstw;
    const uint16_t* s = pB + kb + kh * 32;
    cp16(s, d);
    cp16(s + rstep, d + 4096);
  };

  f32x4 acc[8][4];
#pragma unroll
  for (int i = 0; i < 8; ++i)
#pragma unroll
    for (int j = 0; j < 4; ++j) acc[i][j] = (f32x4){0.f, 0.f, 0.f, 0.f};
  short8 bf[4];

  const int NT = K >> 6;                       // 8 or 32, always even
  // prologue: tile0 fully, tile1 k0; wait tile0 landed, keep tile1.k0 in flight
  stageA(0, 0, 0);  stageB(0, 0, 0);
  stageA(0, 1, 0);  stageB(0, 1, 0);
  stageA(1, 0, 64); stageB(1, 0, 64);
  __builtin_amdgcn_sched_barrier(0);
  asm volatile("s_waitcnt vmcnt(4)");
  __builtin_amdgcn_sched_barrier(0);
  __builtin_amdgcn_s_barrier();

#define DSR(dst, base, OFF)                                                      \
  asm volatile("ds_read_b128 %0, %1 offset:%2" : "=v"(dst) : "v"(base), "i"(OFF))

#define PHASE(BUF, MH, KH, RB, PRE, POST)                                        \
  {                                                                              \
    short8 af[4];                                                                \
    DSR(af[0], ((BUF) ? aB1_ : aB0_), (KH)*16384 + (MH)*4096 + 0*1024);          \
    DSR(af[1], ((BUF) ? aB1_ : aB0_), (KH)*16384 + (MH)*4096 + 1*1024);          \
    DSR(af[2], ((BUF) ? aB1_ : aB0_), (KH)*16384 + (MH)*4096 + 2*1024);          \
    DSR(af[3], ((BUF) ? aB1_ : aB0_), (KH)*16384 + (MH)*4096 + 3*1024);          \
    if (RB) {                                                                    \
      DSR(bf[0], ((BUF) ? bB1_ : bB0_), (KH)*16384 + 0*1024);                    \
      DSR(bf[1], ((BUF) ? bB1_ : bB0_), (KH)*16384 + 1*1024);                    \
      DSR(bf[2], ((BUF) ? bB1_ : bB0_), (KH)*16384 + 2*1024);                    \
      DSR(bf[3], ((BUF) ? bB1_ : bB0_), (KH)*16384 + 3*1024);                    \
    }                                                                            \
    PRE;                                                                         \
    __builtin_amdgcn_sched_barrier(0);                                           \
    __builtin_amdgcn_s_barrier();                                                \
    asm volatile("s_waitcnt lgkmcnt(0)");                                        \
    __builtin_amdgcn_sched_barrier(0);                                           \
    __builtin_amdgcn_s_setprio(1);                                               \
    _Pragma("unroll")                                                            \
    for (int i = 0; i < 4; ++i)                                                  \
      _Pragma("unroll")                                                          \
      for (int j = 0; j < 4; ++j)                                                \
        acc[(MH)*4 + i][j] = __builtin_amdgcn_mfma_f32_16x16x32_bf16(af[i], bf[j], acc[(MH)*4 + i][j], 0, 0, 0); \
    __builtin_amdgcn_s_setprio(0);                                               \
    __builtin_amdgcn_sched_barrier(0);                                           \
    POST;                                                                        \
    __builtin_amdgcn_sched_barrier(0);                                           \
    __builtin_amdgcn_s_barrier();                                                \
  }

  for (int t2 = 0; t2 < NT; t2 += 2) {
    {
      const int t = t2;
      const int kb1 = (t + 1) << 6, kb2 = (t + 2) << 6;
      PHASE(0, 0, 0, 1, if (t + 1 < NT) stageA(1, 1, kb1), {});
      PHASE(0, 1, 0, 0, if (t + 1 < NT) stageB(1, 1, kb1), {});
      PHASE(0, 0, 1, 1, if (t + 2 < NT) stageA(0, 0, kb2), {});
      PHASE(0, 1, 1, 0, if (t + 2 < NT) stageB(0, 0, kb2),
            if (t + 2 < NT) { asm volatile("s_waitcnt vmcnt(4)"); }
            else            { asm volatile("s_waitcnt vmcnt(0)"); });
    }
    {
      const int t = t2 + 1;
      const int kb1 = (t + 1) << 6, kb2 = (t + 2) << 6;
      PHASE(1, 0, 0, 1, if (t + 1 < NT) stageA(0, 1, kb1), {});
      PHASE(1, 1, 0, 0, if (t + 1 < NT) stageB(0, 1, kb1), {});
      PHASE(1, 0, 1, 1, if (t + 2 < NT) stageA(1, 0, kb2), {});
      PHASE(1, 1, 1, 0, if (t + 2 < NT) stageB(1, 0, kb2),
            if (t + 2 < NT) { asm volatile("s_waitcnt vmcnt(4)"); }
            else            { asm volatile("s_waitcnt vmcnt(0)"); });
    }
  }
#undef PHASE
#undef DSR

  // ---- epilogue phase 1: bias+activation in fragment layout -> swizzled LDS (bf16)
  __syncthreads();
  const float bj[4] = {bias[n0 + wn + l15], bias[n0 + wn + 16 + l15],
                       bias[n0 + wn + 32 + l15], bias[n0 + wn + 48 + l15]};
#pragma unroll
  for (int mf = 0; mf < 8; ++mf)
#pragma unroll
    for (int rg = 0; rg < 4; ++rg) {
      const int lrow = wm + mf * 16 + l4 * 4 + rg;   // C/D: row = quad*4+reg
#pragma unroll
      for (int j = 0; j < 4; ++j) {
        const int lcol = wn + j * 16 + l15;          // C/D: col = lane&15
        float v = acc[mf][j][rg] + bj[j];
        if (E == 5) {
          if (n0 + lcol < 1024) v = v > 0.f ? v + 1.f : __expf(v);  // phi = elu+1
        } else if (E == 3) {
          v = gelu_f(v);
        }
        S[lrow * 256 + ((((lcol >> 3) ^ lrow) & 31) * 8) + (lcol & 7)] = f2bf(v);
      }
    }
  __syncthreads();

  // ---- epilogue phase 2: coalesced readback + residual + store (16B/lane)
  uint16_t* outb = (uint16_t*)outp;
  float* outf = (float*)outp;
  const int rr = tid >> 5;          // row within 16-row pass
  const int cb = tid & 31;          // 16B col-block
#pragma unroll
  for (int p = 0; p < 16; ++p) {
    const int lrow = p * 16 + rr;
    const int row = m0 + lrow;
    const int col0 = n0 + cb * 8;
    const uint4 d = *(const uint4*)&S[lrow * 256 + ((cb ^ lrow) & 31) * 8];
    if (E == 5) {
      const size_t offs = (size_t)(col0 >> 9) * ((size_t)ROWST * DD) +
                          (size_t)row * DD + (col0 & 511);
      *(uint4*)&outb[offs] = d;
    } else if (E == 1 || E == 3) {
      *(uint4*)&outb[(size_t)row * N + col0] = d;
    } else {
      const size_t idx = (size_t)row * N + col0;
      const uint4 rd = *(const uint4*)&res[idx];
      float a[8];
      a[0] = bf2f((uint16_t)(d.x & 0xffff)) + bf2f((uint16_t)(rd.x & 0xffff));
      a[1] = bf2f((uint16_t)(d.x >> 16))    + bf2f((uint16_t)(rd.x >> 16));
      a[2] = bf2f((uint16_t)(d.y & 0xffff)) + bf2f((uint16_t)(rd.y & 0xffff));
      a[3] = bf2f((uint16_t)(d.y >> 16))    + bf2f((uint16_t)(rd.y >> 16));
      a[4] = bf2f((uint16_t)(d.z & 0xffff)) + bf2f((uint16_t)(rd.z & 0xffff));
      a[5] = bf2f((uint16_t)(d.z >> 16))    + bf2f((uint16_t)(rd.z >> 16));
      a[6] = bf2f((uint16_t)(d.w & 0xffff)) + bf2f((uint16_t)(rd.w & 0xffff));
      a[7] = bf2f((uint16_t)(d.w >> 16))    + bf2f((uint16_t)(rd.w >> 16));
      if (E == 2) {
        uint4 o;
        o.x = (uint32_t)f2bf(a[0]) | ((uint32_t)f2bf(a[1]) << 16);
        o.y = (uint32_t)f2bf(a[2]) | ((uint32_t)f2bf(a[3]) << 16);
        o.z = (uint32_t)f2bf(a[4]) | ((uint32_t)f2bf(a[5]) << 16);
        o.w = (uint32_t)f2bf(a[6]) | ((uint32_t)f2bf(a[7]) << 16);
        *(uint4*)&outb[idx] = o;
      } else {                       // E == 4: f32 out
        *(float4*)&outf[idx]     = (float4){a[0], a[1], a[2], a[3]};
        *(float4*)&outf[idx + 4] = (float4){a[4], a[5], a[6], a[7]};
      }
    }
  }
}

// ---------------- LayerNorm: one wave per 512-elem row, out bf16 ----------------
template <int BFIN>
__launch_bounds__(256)
__global__ void ln_kernel(const void* __restrict__ inp, const float* __restrict__ gam,
                          const float* __restrict__ bet, uint16_t* __restrict__ out) {
  const int row = blockIdx.x * 4 + (threadIdx.x >> 6);
  const int lane = threadIdx.x & 63;
  const size_t base = (size_t)row * DD + lane * 8;
  float x[8];
  if (BFIN) {
    const uint4 u = *(const uint4*)((const uint16_t*)inp + base);
    x[0] = bf2f((uint16_t)(u.x & 0xffff)); x[1] = bf2f((uint16_t)(u.x >> 16));
    x[2] = bf2f((uint16_t)(u.y & 0xffff)); x[3] = bf2f((uint16_t)(u.y >> 16));
    x[4] = bf2f((uint16_t)(u.z & 0xffff)); x[5] = bf2f((uint16_t)(u.z >> 16));
    x[6] = bf2f((uint16_t)(u.w & 0xffff)); x[7] = bf2f((uint16_t)(u.w >> 16));
  } else {
    const float* f = (const float*)inp + base;
    const float4 a = *(const float4*)f;
    const float4 b = *(const float4*)(f + 4);
    x[0]=a.x; x[1]=a.y; x[2]=a.z; x[3]=a.w; x[4]=b.x; x[5]=b.y; x[6]=b.z; x[7]=b.w;
  }
  float s = 0.f, s2 = 0.f;
#pragma unroll
  for (int j = 0; j < 8; ++j) { s += x[j]; s2 += x[j] * x[j]; }
#pragma unroll
  for (int off = 32; off; off >>= 1) { s += __shfl_xor(s, off, 64); s2 += __shfl_xor(s2, off, 64); }
  const float m = s * (1.f / DD);
  const float rs = rsqrtf(s2 * (1.f / DD) - m * m + 1e-5f);
  uint16_t o[8];
#pragma unroll
  for (int j = 0; j < 8; ++j) {
    const int col = lane * 8 + j;
    o[j] = f2bf((x[j] - m) * rs * gam[col] + bet[col]);
  }
  uint4 w;
  w.x = (uint32_t)o[0] | ((uint32_t)o[1] << 16);
  w.y = (uint32_t)o[2] | ((uint32_t)o[3] << 16);
  w.z = (uint32_t)o[4] | ((uint32_t)o[5] << 16);
  w.w = (uint32_t)o[6] | ((uint32_t)o[7] << 16);
  *(uint4*)(out + base) = w;
}

// ---------------- weight transpose fp32[R,C] -> bf16[C,R] ----------------
__launch_bounds__(256)
__global__ void transpose_bf(const float* __restrict__ in, uint16_t* __restrict__ out,
                             int R, int C) {
  __shared__ float tile[32][33];
  const int tx = threadIdx.x, ty = threadIdx.y;
  const int c0 = blockIdx.x * 32, r0 = blockIdx.y * 32;
#pragma unroll
  for (int i = 0; i < 32; i += 8)
    tile[ty + i][tx] = in[(size_t)(r0 + ty + i) * C + (c0 + tx)];
  __syncthreads();
#pragma unroll
  for (int i = 0; i < 32; i += 8)
    out[(size_t)(c0 + ty + i) * R + (r0 + tx)] = f2bf(tile[tx][ty + i]);
}

__global__ void concat_bias(const float* __restrict__ bq, const float* __restrict__ bk,
                            const float* __restrict__ bv, float* __restrict__ o) {
  const int t = blockIdx.x * 256 + threadIdx.x;
  if (t < 512) o[t] = bq[t];
  else if (t < 1024) o[t] = bk[t - 512];
  else if (t < 1536) o[t] = bv[t - 1024];
}

// ---------------- kv partials via MFMA: kv[b,h,dk,dv] = sum_n pk*v ----------------
__launch_bounds__(256)
__global__ void kv_mfma(const uint16_t* __restrict__ pk, const uint16_t* __restrict__ v,
                        float* __restrict__ kvp, float* __restrict__ ksp) {
  __shared__ __align__(16) uint16_t sT[4][2][64 * 64];  // [wave][pk|v][swizzled]
  __shared__ float ksred[64];
  const int bh = blockIdx.x, b = bh >> 3, h = bh & 7;
  const int t = threadIdx.x, lane = t & 63, w = t >> 6;
  const int l15 = lane & 15, l4 = lane >> 4;
  if (t < 64) ksred[t] = 0.f;
  __syncthreads();

  f32x4 acc[4][4];
#pragma unroll
  for (int i = 0; i < 4; ++i)
#pragma unroll
    for (int j = 0; j < 4; ++j) acc[i][j] = (f32x4){0.f, 0.f, 0.f, 0.f};
  float ks[4] = {0.f, 0.f, 0.f, 0.f};

  const int rl = lane >> 3, cl = (lane & 7) * 8;  // load: 8 rows x 64 cols per round
  for (int sc = 0; sc < 4; ++sc) {
    const int nbase = blockIdx.y * 1024 + w * 256 + sc * 64;
#pragma unroll
    for (int ro = 0; ro < 8; ++ro) {
      const int n = ro * 8 + rl;
      const size_t gofs = ((size_t)(b * NN + nbase + n) * HH + h) * 64 + cl;
      const short8 pv = *(const short8*)(pk + gofs);
      const short8 vv = *(const short8*)(v + gofs);
#pragma unroll
      for (int j = 0; j < 8; ++j) {           // transpose into [dk][n] / [dv][n]
        sT[w][0][swz(cl + j, n)] = (uint16_t)pv[j];
        sT[w][1][swz(cl + j, n)] = (uint16_t)vv[j];
      }
    }
#pragma unroll
    for (int kk = 0; kk < 64; kk += 32) {
      short8 af[4], bfr[4];
#pragma unroll
      for (int i = 0; i < 4; ++i)
        af[i] = *(const short8*)&sT[w][0][swz(i * 16 + l15, kk + l4 * 8)];
#pragma unroll
      for (int j = 0; j < 4; ++j)
        bfr[j] = *(const short8*)&sT[w][1][swz(j * 16 + l15, kk + l4 * 8)];
#pragma unroll
      for (int i = 0; i < 4; ++i) {
#pragma unroll
        for (int e = 0; e < 8; ++e) ks[i] += bf2f((uint16_t)af[i][e]);
#pragma unroll
        for (int j = 0; j < 4; ++j)
          acc[i][j] = __builtin_amdgcn_mfma_f32_16x16x32_bf16(af[i], bfr[j], acc[i][j], 0, 0, 0);
      }
    }
  }
#pragma unroll
  for (int i = 0; i < 4; ++i) {
    float s = ks[i];
    s += __shfl_xor(s, 16, 64); s += __shfl_xor(s, 32, 64);
    if (l4 == 0) atomicAdd(&ksred[i * 16 + l15], s);
  }
  __syncthreads();
  float* red = (float*)&sT[0][0][0];
  if (w > 0) {
#pragma unroll
    for (int i = 0; i < 4; ++i)
#pragma unroll
      for (int r = 0; r < 4; ++r)
#pragma unroll
        for (int j = 0; j < 4; ++j)
          red[(w - 1) * 4096 + (i * 16 + l4 * 4 + r) * 64 + j * 16 + l15] = acc[i][j][r];
  }
  __syncthreads();
  if (w == 0) {
    float* dst = kvp + ((size_t)bh * 16 + blockIdx.y) * 4096;
#pragma unroll
    for (int i = 0; i < 4; ++i)
#pragma unroll
      for (int r = 0; r < 4; ++r)
#pragma unroll
        for (int j = 0; j < 4; ++j) {
          const int e = (i * 16 + l4 * 4 + r) * 64 + j * 16 + l15;
          dst[e] = acc[i][j][r] + red[e] + red[4096 + e] + red[8192 + e];
        }
  }
  if (t < 64) ksp[((size_t)bh * 16 + blockIdx.y) * 64 + t] = ksred[t];
}

// sum the 16 per-chunk partials. grid (32, 17): y==16 handles ksum.
__launch_bounds__(256)
__global__ void kv_reduce(const float* __restrict__ kvp, const float* __restrict__ ksp,
                          float* __restrict__ kv, float* __restrict__ ksum) {
  const int bh = blockIdx.x;
  if (blockIdx.y == 16) {
    if (threadIdx.x < 64) {
      float s = 0.f;
      for (int c = 0; c < 16; ++c) s += ksp[((size_t)bh * 16 + c) * 64 + threadIdx.x];
      ksum[bh * 64 + threadIdx.x] = s;
    }
    return;
  }
  const int e = blockIdx.y * 256 + threadIdx.x;
  float s = 0.f;
  for (int c = 0; c < 16; ++c) s += kvp[((size_t)bh * 16 + c) * 4096 + e];
  kv[(size_t)bh * 4096 + e] = s;
}

// ---------------- attn via MFMA: attn = (pq @ kv) / (pq . ksum + eps) ----------------
__launch_bounds__(256)
__global__ void attn_mfma(const uint16_t* __restrict__ pq, const float* __restrict__ kv,
                          const float* __restrict__ ksum, uint16_t* __restrict__ attn) {
  __shared__ __align__(16) uint16_t kvT[64 * 64];   // B: [dv][dk] swizzled, bf16
  __shared__ float ksS[64];
  __shared__ float denS[4][64];
  const int bh = blockIdx.x, b = bh >> 3, h = bh & 7;
  const int t = threadIdx.x, lane = t & 63, w = t >> 6;
  const int l15 = lane & 15, l4 = lane >> 4;
  const float* kvb = kv + (size_t)bh * 4096;
#pragma unroll
  for (int u = 0; u < 16; ++u) {
    const int e = u * 256 + t;                       // e = dk*64 + dv
    kvT[swz(e & 63, e >> 6)] = f2bf(kvb[e]);
  }
  if (t < 64) ksS[t] = ksum[bh * 64 + t];
  __syncthreads();

  float ksr[16];
#pragma unroll
  for (int kk2 = 0; kk2 < 2; ++kk2) {
    const float4 k0 = *(const float4*)&ksS[kk2 * 32 + l4 * 8];
    const float4 k1 = *(const float4*)&ksS[kk2 * 32 + l4 * 8 + 4];
    ksr[kk2 * 8 + 0] = k0.x; ksr[kk2 * 8 + 1] = k0.y; ksr[kk2 * 8 + 2] = k0.z; ksr[kk2 * 8 + 3] = k0.w;
    ksr[kk2 * 8 + 4] = k1.x; ksr[kk2 * 8 + 5] = k1.y; ksr[kk2 * 8 + 6] = k1.z; ksr[kk2 * 8 + 7] = k1.w;
  }
  short8 bfrg[2][4];
#pragma unroll
  for (int kk2 = 0; kk2 < 2; ++kk2)
#pragma unroll
    for (int j = 0; j < 4; ++j)
      bfrg[kk2][j] = *(const short8*)&kvT[swz(j * 16 + l15, kk2 * 32 + l4 * 8)];

  const int n0w = blockIdx.y * 256 + w * 64;
  f32x4 acc[4][4];
#pragma unroll
  for (int i = 0; i < 4; ++i)
#pragma unroll
    for (int j = 0; j < 4; ++j) acc[i][j] = (f32x4){0.f, 0.f, 0.f, 0.f};
  float den[4] = {0.f, 0.f, 0.f, 0.f};

#pragma unroll
  for (int i = 0; i < 4; ++i) {
    const int n = n0w + i * 16 + l15;
    const size_t abase = ((size_t)(b * NN + n) * HH + h) * 64 + l4 * 8;
#pragma unroll
    for (int kk2 = 0; kk2 < 2; ++kk2) {
      const short8 af = *(const short8*)(pq + abase + kk2 * 32);
#pragma unroll
      for (int e = 0; e < 8; ++e) den[i] += bf2f((uint16_t)af[e]) * ksr[kk2 * 8 + e];
#pragma unroll
      for (int j = 0; j < 4; ++j)
        acc[i][j] = __builtin_amdgcn_mfma_f32_16x16x32_bf16(af, bfrg[kk2][j], acc[i][j], 0, 0, 0);
    }
  }
#pragma unroll
  for (int i = 0; i < 4; ++i) {
    float s = den[i];
    s += __shfl_xor(s, 16, 64); s += __shfl_xor(s, 32, 64);
    if (l4 == 0) denS[w][i * 16 + l15] = s;          // same-wave LDS, in-order
  }
#pragma unroll
  for (int i = 0; i < 4; ++i)
#pragma unroll
    for (int r = 0; r < 4; ++r) {
      const float z = 1.f / (denS[w][i * 16 + l4 * 4 + r] + 1e-6f);
      const int n = n0w + i * 16 + l4 * 4 + r;
      const size_t ob = ((size_t)(b * NN + n) * HH + h) * 64;
#pragma unroll
      for (int j = 0; j < 4; ++j)
        attn[ob + j * 16 + l15] = f2bf(acc[i][j][r] * z);
    }
}

// ---------------- host launch ----------------
extern "C" void kernel_launch(void* const* d_in, const int* in_sizes, int n_in,
                              void* d_out, int out_size, void* d_ws, size_t ws_size,
                              hipStream_t stream) {
  (void)in_sizes; (void)n_in; (void)out_size;
  const float* x    = (const float*)d_in[0];
  const float* ln1g = (const float*)d_in[1];
  const float* ln1b = (const float*)d_in[2];
  const float* Wq   = (const float*)d_in[3];
  const float* bq   = (const float*)d_in[4];
  const float* Wk   = (const float*)d_in[5];
  const float* bk   = (const float*)d_in[6];
  const float* Wv   = (const float*)d_in[7];
  const float* bv   = (const float*)d_in[8];
  const float* Wo   = (const float*)d_in[9];
  const float* bo   = (const float*)d_in[10];
  const float* ln2g = (const float*)d_in[11];
  const float* ln2b = (const float*)d_in[12];
  const float* W1   = (const float*)d_in[13];
  const float* b1   = (const float*)d_in[14];
  const float* W2   = (const float*)d_in[15];
  const float* b2   = (const float*)d_in[16];

  if (ws_size < 409000000ULL) return;

  char* p = (char*)d_ws;
  auto alloc = [&](size_t bytes) -> char* {
    char* r = p; p += (bytes + 255) & ~(size_t)255; return r;
  };
  uint16_t* Hb  = (uint16_t*)alloc((size_t)ROWST * DD * 2);   // h (LN1 out)
  uint16_t* PQ  = (uint16_t*)alloc((size_t)ROWST * DD * 2);   // phi(q); later h2
  uint16_t* PK  = (uint16_t*)alloc((size_t)ROWST * DD * 2);   // phi(k); later hres
  uint16_t* PV  = (uint16_t*)alloc((size_t)ROWST * DD * 2);   // v; later attn
  uint16_t* U   = (uint16_t*)alloc((size_t)32768 * HIDN * 2); // MLP hidden chunk (also kv scratch)
  uint16_t* WqkvT = (uint16_t*)alloc((size_t)1536 * DD * 2);
  uint16_t* WoT = (uint16_t*)alloc((size_t)DD * DD * 2);
  uint16_t* W1T = (uint16_t*)alloc((size_t)HIDN * DD * 2);
  uint16_t* W2T = (uint16_t*)alloc((size_t)DD * HIDN * 2);
  float*    bqkv = (float*)alloc(1536 * 4);
  float* KVP = (float*)U;                  // 512*4096 fp32 = 8 MiB
  float* KSP = KVP + 512 * 4096;           // 512*64 fp32
  float* KV  = KSP + 512 * 64;             // 32*4096 fp32
  float* KS  = KV + 32 * 4096;             // 32*64 fp32

  const dim3 tb(32, 8);
  transpose_bf<<<dim3(16, 16), tb, 0, stream>>>(Wq, WqkvT, DD, DD);
  transpose_bf<<<dim3(16, 16), tb, 0, stream>>>(Wk, WqkvT + 512 * 512, DD, DD);
  transpose_bf<<<dim3(16, 16), tb, 0, stream>>>(Wv, WqkvT + 2 * 512 * 512, DD, DD);
  transpose_bf<<<dim3(16, 16), tb, 0, stream>>>(Wo, WoT, DD, DD);
  transpose_bf<<<dim3(64, 16), tb, 0, stream>>>(W1, W1T, DD, HIDN);
  transpose_bf<<<dim3(16, 64), tb, 0, stream>>>(W2, W2T, HIDN, DD);
  concat_bias<<<6, 256, 0, stream>>>(bq, bk, bv, bqkv);

  // h = LN1(x)
  ln_kernel<0><<<ROWST / 4, 256, 0, stream>>>(x, ln1g, ln1b, Hb);
  // fused qkv: [pq|pk|v] = epi(h @ Wqkv + b)
  gemm256<5><<<dim3(6, 256), 512, 0, stream>>>(Hb, WqkvT, bqkv, nullptr, PQ, ROWST, 1536, DD);
  // kv / ksum via MFMA partials + reduce
  kv_mfma<<<dim3(32, 16), 256, 0, stream>>>(PK, PV, KVP, KSP);
  kv_reduce<<<dim3(32, 17), 256, 0, stream>>>(KVP, KSP, KV, KS);
  // attn (normalized) -> PV
  attn_mfma<<<dim3(32, 64), 256, 0, stream>>>(PQ, KV, KS, PV);
  // hres = attn@Wo + bo + h -> PK
  gemm256<2><<<dim3(2, 256), 512, 0, stream>>>(PV, WoT, bo, Hb, PK, ROWST, DD, DD);
  // h2 = LN2(hres) -> PQ
  ln_kernel<1><<<ROWST / 4, 256, 0, stream>>>(PK, ln2g, ln2b, PQ);
  // MLP in 2 row-chunks: out = h2 + gelu(h2@W1+b1)@W2 + b2
  for (int c = 0; c < 2; ++c) {
    const uint16_t* h2c = PQ + (size_t)c * 32768 * DD;
    gemm256<3><<<dim3(8, 128), 512, 0, stream>>>(h2c, W1T, b1, nullptr, U, 32768, HIDN, DD);
    gemm256<4><<<dim3(2, 128), 512, 0, stream>>>(U, W2T, b2, h2c,
        (float*)d_out + (size_t)c * 32768 * DD, 32768, DD, HIDN);
  }
}